// Round 6
// baseline (648.483 us; speedup 1.0000x reference)
//
#include <hip/hip_runtime.h>
#include <hip/hip_bf16.h>

// GraphNet: N=50000 nodes, F=128 feats, H=128, MH=256, E=800000 edges
// Inputs FP32; bf16 workspace copies for MFMA; fp32 MFMA accumulation.
#define NN 50000
#define F 128
#define EE 800000
#define MHD 256

typedef __attribute__((ext_vector_type(8))) short bf16x8;
typedef __attribute__((ext_vector_type(4))) float f32x4;
typedef __attribute__((ext_vector_type(16))) float f32x16;

__device__ __forceinline__ float b2f(unsigned short u) {
    union { unsigned int i; float f; } v; v.i = ((unsigned)u) << 16; return v.f;
}
__device__ __forceinline__ unsigned short f2b(float f) {
    unsigned int x = __float_as_uint(f);
    unsigned int r = x + 0x7fffu + ((x >> 16) & 1u);   // RNE
    return (unsigned short)(r >> 16);
}

// ---------------- fp32 -> bf16 cast of x ----------------
__global__ __launch_bounds__(256) void cast_x_kernel(
    const float* __restrict__ in, unsigned short* __restrict__ out) {
    int i = (blockIdx.x * 256 + threadIdx.x) * 4;
    float4 v = *(const float4*)(in + i);
    ushort4 o; o.x = f2b(v.x); o.y = f2b(v.y); o.z = f2b(v.z); o.w = f2b(v.w);
    *(ushort4*)(out + i) = o;
}

// ---------------- fp32 -> bf16 cast of the 4 node-layer weights ----------------
__global__ __launch_bounds__(256) void cast_w_kernel(
    const float* __restrict__ W1l, const float* __restrict__ W1r,
    const float* __restrict__ W2l, const float* __restrict__ W2r,
    unsigned short* __restrict__ wb) {
    int i = (blockIdx.x * 256 + threadIdx.x) * 4;        // 65536 elems / 4
    const float* p;
    if (i < 16384)      p = W1l + i;
    else if (i < 32768) p = W1r + (i - 16384);
    else if (i < 49152) p = W2l + (i - 32768);
    else                p = W2r + (i - 49152);
    float4 v = *(const float4*)p;
    ushort4 o; o.x = f2b(v.x); o.y = f2b(v.y); o.z = f2b(v.z); o.w = f2b(v.w);
    *(ushort4*)(wb + i) = o;
}

// ---------------- Wm1 fp32 -> bf16, reordered into 32x32x16 B-fragment order ----------------
// frag-block q = (s*2+nt2)*16 + ks (0..127); lane l holds Wm1[sn*32+(l&31)][ks*16+(l>>5)*8 ..+8]
__global__ __launch_bounds__(256) void frag_wm1_kernel(
    const float* __restrict__ Wm1, unsigned short* __restrict__ wm1f) {
    int gid = blockIdx.x * 256 + threadIdx.x;            // 8192 threads
    int l = gid & 63;
    int q = gid >> 6;                                    // 0..127
    int ks = q & 15, sn = q >> 4;                        // sn = s*2+nt2
    int row = sn * 32 + (l & 31);
    int col = ks * 16 + (l >> 5) * 8;
    const float* p = Wm1 + row * MHD + col;
    float4 v0 = *(const float4*)p;
    float4 v1 = *(const float4*)(p + 4);
    unsigned short o[8];
    o[0]=f2b(v0.x); o[1]=f2b(v0.y); o[2]=f2b(v0.z); o[3]=f2b(v0.w);
    o[4]=f2b(v1.x); o[5]=f2b(v1.y); o[6]=f2b(v1.z); o[7]=f2b(v1.w);
    *(bf16x8*)(wm1f + (size_t)gid * 8) = *(bf16x8*)o;
}

// ---------------- edge_index canonicalize -> int32 src/dst ----------------
__global__ __launch_bounds__(256) void edge_cvt_kernel(
    const int* __restrict__ ei, int* __restrict__ s32, int* __restrict__ d32) {
    __shared__ int isI64;
    if (threadIdx.x == 0) {
        int z = 0;
        for (int i = 1; i < 128; i += 2) z |= ei[i];
        isI64 = (z == 0) ? 1 : 0;
    }
    __syncthreads();
    int e = blockIdx.x * 256 + threadIdx.x;
    if (e >= EE) return;
    if (isI64) {
        const long long* e64 = (const long long*)ei;
        s32[e] = (int)e64[e];
        d32[e] = (int)e64[EE + e];
    } else {
        s32[e] = ei[e];
        d32[e] = ei[EE + e];
    }
}

// ---------------- CSR build: histogram -> scan -> fill ----------------
__global__ __launch_bounds__(256) void hist_kernel(
    const int* __restrict__ d32, int* __restrict__ deg) {
    int e = blockIdx.x * 256 + threadIdx.x;
    if (e < EE) atomicAdd(&deg[d32[e]], 1);
}

#define SCAN_T 1024
#define SCHUNK 49   // 1024*49 = 50176 >= NN
__global__ __launch_bounds__(1024) void scan_kernel(
    const int* __restrict__ deg, int* __restrict__ rowstart, int* __restrict__ cursor) {
    __shared__ int part[SCAN_T];
    int t = threadIdx.x;
    int beg = t * SCHUNK, end = min(beg + SCHUNK, NN);
    int s = 0;
    for (int i = beg; i < end; i++) s += deg[i];
    part[t] = s;
    __syncthreads();
    for (int off = 1; off < SCAN_T; off <<= 1) {
        int v = (t >= off) ? part[t - off] : 0;
        __syncthreads();
        part[t] += v;
        __syncthreads();
    }
    int run = (t == 0) ? 0 : part[t - 1];
    for (int i = beg; i < end; i++) {
        rowstart[i] = run; cursor[i] = run; run += deg[i];
    }
    if (t == SCAN_T - 1) rowstart[NN] = run;
}

__global__ __launch_bounds__(256) void fill_kernel(
    const int* __restrict__ s32, const int* __restrict__ d32,
    int* __restrict__ cursor, int* __restrict__ nbr) {
    int e = blockIdx.x * 256 + threadIdx.x;
    if (e < EE) {
        int p = atomicAdd(&cursor[d32[e]], 1);
        nbr[p] = s32[e];
    }
}

// ---------------- gather aggregation + mean ----------------
// One wave/node; 16 lanes x 16B per neighbor row -> 4 nbrs/load; 4 loads in flight.
__global__ __launch_bounds__(256) void agg_gather_kernel(
    const unsigned short* __restrict__ xin,
    const int* __restrict__ nbr, const int* __restrict__ rowstart,
    unsigned short* __restrict__ aggb) {
    int wave = threadIdx.x >> 6, lane = threadIdx.x & 63;
    int node = blockIdx.x * 4 + wave;
    if (node >= NN) return;
    int part = lane >> 4;                    // 0..3: which neighbor in group of 4
    int col8 = (lane & 15) * 8;              // 8 feats per lane
    int beg = rowstart[node], end = rowstart[node + 1];
    float a[8] = {0,0,0,0,0,0,0,0};
    float b[8] = {0,0,0,0,0,0,0,0};
    int j = beg + part;
    for (; j + 12 < end; j += 16) {          // 4 outstanding 16B loads, 16 nbrs/wave in flight
        int s0 = nbr[j], s1 = nbr[j + 4], s2 = nbr[j + 8], s3 = nbr[j + 12];
        bf16x8 v0 = *(const bf16x8*)(xin + (size_t)s0 * F + col8);
        bf16x8 v1 = *(const bf16x8*)(xin + (size_t)s1 * F + col8);
        bf16x8 v2 = *(const bf16x8*)(xin + (size_t)s2 * F + col8);
        bf16x8 v3 = *(const bf16x8*)(xin + (size_t)s3 * F + col8);
        for (int i = 0; i < 8; i++) a[i] += b2f((unsigned short)v0[i]);
        for (int i = 0; i < 8; i++) b[i] += b2f((unsigned short)v1[i]);
        for (int i = 0; i < 8; i++) a[i] += b2f((unsigned short)v2[i]);
        for (int i = 0; i < 8; i++) b[i] += b2f((unsigned short)v3[i]);
    }
    for (; j < end; j += 4) {
        int s0 = nbr[j];
        bf16x8 v0 = *(const bf16x8*)(xin + (size_t)s0 * F + col8);
        for (int i = 0; i < 8; i++) a[i] += b2f((unsigned short)v0[i]);
    }
    float inv = 1.0f / fmaxf((float)(end - beg), 1.0f);
    unsigned short o[8];
    for (int i = 0; i < 8; i++) {
        float v = a[i] + b[i];
        v += __shfl_xor(v, 16);
        v += __shfl_xor(v, 32);
        o[i] = f2b(v * inv);
    }
    if (part == 0)
        *(bf16x8*)(aggb + (size_t)node * F + col8) = *(bf16x8*)o;
}

// ---------------- fused SAGE combine: out = relu(A1@W1^T + bias + A2@W2^T) ----------------
__global__ __launch_bounds__(256) void node_gemm_kernel(
    const unsigned short* __restrict__ A1, const unsigned short* __restrict__ A2,
    const unsigned short* __restrict__ W1, const unsigned short* __restrict__ W2,
    const float* __restrict__ bias,
    unsigned short* __restrict__ out) {
    int wave = threadIdx.x >> 6, lane = threadIdx.x & 63;
    int c = lane & 15, q = lane >> 4;
    int m0 = (blockIdx.x * 4 + wave) * 16;
    if (m0 >= NN) return;
    f32x4 acc[8];
    for (int nt = 0; nt < 8; nt++) {
        float b = bias[nt * 16 + c];
        acc[nt] = (f32x4){b, b, b, b};
    }
    int mrow = m0 + c; if (mrow > NN - 1) mrow = NN - 1;
    for (int op = 0; op < 2; op++) {
        const unsigned short* ap = (op ? A2 : A1) + (size_t)mrow * F + q * 8;
        const unsigned short* W  = op ? W2 : W1;
        for (int kb = 0; kb < 4; kb++) {
            bf16x8 a = *(const bf16x8*)(ap + kb * 32);
            for (int nt = 0; nt < 8; nt++) {
                bf16x8 b = *(const bf16x8*)(W + (size_t)(nt * 16 + c) * F + kb * 32 + q * 8);
                acc[nt] = __builtin_amdgcn_mfma_f32_16x16x32_bf16(a, b, acc[nt], 0, 0, 0);
            }
        }
    }
    for (int nt = 0; nt < 8; nt++) {
        for (int r = 0; r < 4; r++) {
            int node = m0 + q * 4 + r;
            if (node < NN) {
                float v = fmaxf(acc[nt][r], 0.0f);
                out[(size_t)node * F + nt * 16 + c] = f2b(v);
            }
        }
    }
}

// ---------------- edge MLP, 32x32x16 MFMA, 2 m-tiles per wave ----------------
// 64 edges/wave, 256/block. Each ds_read_b128 B-frag feeds TWO independent MFMA chains.
// __launch_bounds__(256,1): VGPR cap 512 -> no scratch spill (R5 spilled ~100MB at cap 128).
// A: m=lane&31, k=(lane>>5)*8+j. B: n=lane&31, k=(lane>>5)*8+j.
// C/D: col=lane&31, row=(reg&3)+8*(reg>>2)+4*(lane>>5)  (m74/m101-verified).
__global__ __launch_bounds__(256, 1) void edge_mlp_kernel(
    const unsigned short* __restrict__ h,
    const int* __restrict__ src, const int* __restrict__ dst,
    const unsigned short* __restrict__ wm1f, const float* __restrict__ bm1,
    const float* __restrict__ Wm2, const float* __restrict__ bm2,
    float* __restrict__ out) {
    __shared__ unsigned short wlds[16384];   // 32 KB: one s-quarter
    int t = threadIdx.x;
    int wave = t >> 6, lane = t & 63, c = lane & 31, q5 = lane >> 5;
    int e0 = blockIdx.x * 256 + wave * 64;   // 64 edges per wave
    int eA = e0 + c, eB = e0 + 32 + c;
    int snA = src[eA], dnA = dst[eA];
    int snB = src[eB], dnB = dst[eB];

    // gather A-fragments once per m-tile: ef = concat(h[src], h[dst]), k = kf*16 + q5*8
    bf16x8 af0[16], af1[16];
#pragma unroll
    for (int kf = 0; kf < 16; kf++) {
        int k0 = kf * 16 + q5 * 8;
        const unsigned short* baseA = (k0 < 128) ? (h + (size_t)snA * F) : (h + (size_t)dnA * F);
        const unsigned short* baseB = (k0 < 128) ? (h + (size_t)snB * F) : (h + (size_t)dnB * F);
        af0[kf] = *(const bf16x8*)(baseA + (k0 & 127));
        af1[kf] = *(const bf16x8*)(baseB + (k0 & 127));
    }

    float po0[16], po1[16];
#pragma unroll
    for (int r = 0; r < 16; r++) { po0[r] = 0.f; po1[r] = 0.f; }

    for (int s = 0; s < 4; s++) {
        __syncthreads();
        const bf16x8* gsrc = (const bf16x8*)(wm1f + s * 16384);
        bf16x8* ldst = (bf16x8*)wlds;
#pragma unroll
        for (int i = 0; i < 8; i++) {
            int idx = i * 256 + t;
            ldst[idx] = gsrc[idx];
        }
        __syncthreads();
        for (int nt2 = 0; nt2 < 2; nt2++) {
            int o = s * 64 + nt2 * 32 + c;
            float bv = bm1[o];
            f32x16 acc0, acc1;
#pragma unroll
            for (int r = 0; r < 16; r++) { acc0[r] = bv; acc1[r] = bv; }
            const bf16x8* bbase = (const bf16x8*)(wlds) + nt2 * 16 * 64;
#pragma unroll
            for (int ks = 0; ks < 16; ks++) {
                bf16x8 bf = bbase[ks * 64 + lane];
                acc0 = __builtin_amdgcn_mfma_f32_32x32x16_bf16(af0[ks], bf, acc0, 0, 0, 0);
                acc1 = __builtin_amdgcn_mfma_f32_32x32x16_bf16(af1[ks], bf, acc1, 0, 0, 0);
            }
            float w2 = Wm2[o];
#pragma unroll
            for (int r = 0; r < 16; r++) {
                po0[r] += fmaxf(acc0[r], 0.0f) * w2;
                po1[r] += fmaxf(acc1[r], 0.0f) * w2;
            }
        }
    }
    // reduce over the 32 output cols (lanes differing in bits 0..4)
    float b2 = bm2[0];
#pragma unroll
    for (int r = 0; r < 16; r++) {
        float v0 = po0[r], v1 = po1[r];
        v0 += __shfl_xor(v0, 1);  v1 += __shfl_xor(v1, 1);
        v0 += __shfl_xor(v0, 2);  v1 += __shfl_xor(v1, 2);
        v0 += __shfl_xor(v0, 4);  v1 += __shfl_xor(v1, 4);
        v0 += __shfl_xor(v0, 8);  v1 += __shfl_xor(v1, 8);
        v0 += __shfl_xor(v0, 16); v1 += __shfl_xor(v1, 16);
        if (c == 0) {
            int row = (r & 3) + 8 * (r >> 2) + 4 * q5;
            out[e0 + row] = v0 + b2;
            out[e0 + 32 + row] = v1 + b2;
        }
    }
}

extern "C" void kernel_launch(void* const* d_in, const int* in_sizes, int n_in,
                              void* d_out, int out_size, void* d_ws, size_t ws_size,
                              hipStream_t stream) {
    const float* x   = (const float*)d_in[0];
    const int*   ei  = (const int*)d_in[1];
    const float* W1l = (const float*)d_in[2];
    const float* b1l = (const float*)d_in[3];
    const float* W1r = (const float*)d_in[4];
    const float* W2l = (const float*)d_in[5];
    const float* b2l = (const float*)d_in[6];
    const float* W2r = (const float*)d_in[7];
    const float* Wm1 = (const float*)d_in[8];
    const float* bm1 = (const float*)d_in[9];
    const float* Wm2 = (const float*)d_in[10];
    const float* bm2 = (const float*)d_in[11];

    char* ws = (char*)d_ws;
    unsigned short* xb       = (unsigned short*)(ws);
    unsigned short* h1       = (unsigned short*)(ws + 12800000);
    unsigned short* h2       = (unsigned short*)(ws + 25600000);
    unsigned short* aggb     = (unsigned short*)(ws + 38400000);
    unsigned short* wb       = (unsigned short*)(ws + 51200000);
    int*            s32      = (int*)(ws + 51462144);
    int*            d32      = (int*)(ws + 54662144);
    int*            deg      = (int*)(ws + 57862144);
    int*            rowstart = (int*)(ws + 58062208);
    int*            cursor   = (int*)(ws + 58262272);
    int*            nbr      = (int*)(ws + 58462336);
    float*          outp     = (float*)d_out;

    const unsigned short* w1l_b = wb;
    const unsigned short* w1r_b = wb + 16384;
    const unsigned short* w2l_b = wb + 32768;
    const unsigned short* w2r_b = wb + 49152;
    unsigned short*       wm1f  = wb + 65536;        // 65536 elems, fragment-ordered

    // prep: casts + fragment reorder + indices + CSR build
    cast_x_kernel<<<6250, 256, 0, stream>>>(x, xb);
    cast_w_kernel<<<64, 256, 0, stream>>>(W1l, W1r, W2l, W2r, wb);
    frag_wm1_kernel<<<32, 256, 0, stream>>>(Wm1, wm1f);
    edge_cvt_kernel<<<3125, 256, 0, stream>>>(ei, s32, d32);
    hipMemsetAsync(deg, 0, 200064, stream);
    hist_kernel<<<3125, 256, 0, stream>>>(d32, deg);
    scan_kernel<<<1, 1024, 0, stream>>>(deg, rowstart, cursor);
    fill_kernel<<<3125, 256, 0, stream>>>(s32, d32, cursor, nbr);

    // layer 1
    agg_gather_kernel<<<12500, 256, 0, stream>>>(xb, nbr, rowstart, aggb);
    node_gemm_kernel<<<782, 256, 0, stream>>>(aggb, xb, w1l_b, w1r_b, b1l, h1);
    // layer 2
    agg_gather_kernel<<<12500, 256, 0, stream>>>(h1, nbr, rowstart, aggb);
    node_gemm_kernel<<<782, 256, 0, stream>>>(aggb, h1, w2l_b, w2r_b, b2l, h2);
    // edge MLP
    edge_mlp_kernel<<<3125, 256, 0, stream>>>(h2, s32, d32, wm1f, bm1, Wm2, bm2, outp);
}

// Round 7
// 576.456 us; speedup vs baseline: 1.1249x; 1.1249x over previous
//
#include <hip/hip_runtime.h>
#include <hip/hip_bf16.h>

// GraphNet: N=50000 nodes, F=128 feats, H=128, MH=256, E=800000 edges
// Inputs FP32; bf16 workspace copies for MFMA; fp32 MFMA accumulation.
#define NN 50000
#define F 128
#define EE 800000
#define MHD 256

typedef __attribute__((ext_vector_type(8))) short bf16x8;
typedef __attribute__((ext_vector_type(4))) float f32x4;
typedef __attribute__((ext_vector_type(16))) float f32x16;

__device__ __forceinline__ float b2f(unsigned short u) {
    union { unsigned int i; float f; } v; v.i = ((unsigned)u) << 16; return v.f;
}
__device__ __forceinline__ unsigned short f2b(float f) {
    unsigned int x = __float_as_uint(f);
    unsigned int r = x + 0x7fffu + ((x >> 16) & 1u);   // RNE
    return (unsigned short)(r >> 16);
}

// ---------------- fp32 -> bf16 cast of x ----------------
__global__ __launch_bounds__(256) void cast_x_kernel(
    const float* __restrict__ in, unsigned short* __restrict__ out) {
    int i = (blockIdx.x * 256 + threadIdx.x) * 4;
    float4 v = *(const float4*)(in + i);
    ushort4 o; o.x = f2b(v.x); o.y = f2b(v.y); o.z = f2b(v.z); o.w = f2b(v.w);
    *(ushort4*)(out + i) = o;
}

// ---------------- fp32 -> bf16 cast of the 4 node-layer weights ----------------
__global__ __launch_bounds__(256) void cast_w_kernel(
    const float* __restrict__ W1l, const float* __restrict__ W1r,
    const float* __restrict__ W2l, const float* __restrict__ W2r,
    unsigned short* __restrict__ wb) {
    int i = (blockIdx.x * 256 + threadIdx.x) * 4;        // 65536 elems / 4
    const float* p;
    if (i < 16384)      p = W1l + i;
    else if (i < 32768) p = W1r + (i - 16384);
    else if (i < 49152) p = W2l + (i - 32768);
    else                p = W2r + (i - 49152);
    float4 v = *(const float4*)p;
    ushort4 o; o.x = f2b(v.x); o.y = f2b(v.y); o.z = f2b(v.z); o.w = f2b(v.w);
    *(ushort4*)(wb + i) = o;
}

// ---------------- Wm1 fp32 -> bf16, reordered into 32x32x16 B-fragment order ----------------
// frag-block q = (s*2+nt2)*16 + ks (0..127); lane l holds Wm1[sn*32+(l&31)][ks*16+(l>>5)*8 ..+8]
__global__ __launch_bounds__(256) void frag_wm1_kernel(
    const float* __restrict__ Wm1, unsigned short* __restrict__ wm1f) {
    int gid = blockIdx.x * 256 + threadIdx.x;            // 8192 threads
    int l = gid & 63;
    int q = gid >> 6;                                    // 0..127
    int ks = q & 15, sn = q >> 4;                        // sn = s*2+nt2
    int row = sn * 32 + (l & 31);
    int col = ks * 16 + (l >> 5) * 8;
    const float* p = Wm1 + row * MHD + col;
    float4 v0 = *(const float4*)p;
    float4 v1 = *(const float4*)(p + 4);
    unsigned short o[8];
    o[0]=f2b(v0.x); o[1]=f2b(v0.y); o[2]=f2b(v0.z); o[3]=f2b(v0.w);
    o[4]=f2b(v1.x); o[5]=f2b(v1.y); o[6]=f2b(v1.z); o[7]=f2b(v1.w);
    *(bf16x8*)(wm1f + (size_t)gid * 8) = *(bf16x8*)o;
}

// ---------------- edge_index canonicalize -> int32 src/dst ----------------
__global__ __launch_bounds__(256) void edge_cvt_kernel(
    const int* __restrict__ ei, int* __restrict__ s32, int* __restrict__ d32) {
    __shared__ int isI64;
    if (threadIdx.x == 0) {
        int z = 0;
        for (int i = 1; i < 128; i += 2) z |= ei[i];
        isI64 = (z == 0) ? 1 : 0;
    }
    __syncthreads();
    int e = blockIdx.x * 256 + threadIdx.x;
    if (e >= EE) return;
    if (isI64) {
        const long long* e64 = (const long long*)ei;
        s32[e] = (int)e64[e];
        d32[e] = (int)e64[EE + e];
    } else {
        s32[e] = ei[e];
        d32[e] = ei[EE + e];
    }
}

// ---------------- CSR build: histogram -> scan -> fill ----------------
__global__ __launch_bounds__(256) void hist_kernel(
    const int* __restrict__ d32, int* __restrict__ deg) {
    int e = blockIdx.x * 256 + threadIdx.x;
    if (e < EE) atomicAdd(&deg[d32[e]], 1);
}

#define SCAN_T 1024
#define SCHUNK 49   // 1024*49 = 50176 >= NN
__global__ __launch_bounds__(1024) void scan_kernel(
    const int* __restrict__ deg, int* __restrict__ rowstart, int* __restrict__ cursor) {
    __shared__ int part[SCAN_T];
    int t = threadIdx.x;
    int beg = t * SCHUNK, end = min(beg + SCHUNK, NN);
    int s = 0;
    for (int i = beg; i < end; i++) s += deg[i];
    part[t] = s;
    __syncthreads();
    for (int off = 1; off < SCAN_T; off <<= 1) {
        int v = (t >= off) ? part[t - off] : 0;
        __syncthreads();
        part[t] += v;
        __syncthreads();
    }
    int run = (t == 0) ? 0 : part[t - 1];
    for (int i = beg; i < end; i++) {
        rowstart[i] = run; cursor[i] = run; run += deg[i];
    }
    if (t == SCAN_T - 1) rowstart[NN] = run;
}

__global__ __launch_bounds__(256) void fill_kernel(
    const int* __restrict__ s32, const int* __restrict__ d32,
    int* __restrict__ cursor, int* __restrict__ nbr) {
    int e = blockIdx.x * 256 + threadIdx.x;
    if (e < EE) {
        int p = atomicAdd(&cursor[d32[e]], 1);
        nbr[p] = s32[e];
    }
}

// ---------------- gather aggregation + mean ----------------
// One wave/node; 16 lanes x 16B per neighbor row -> 4 nbrs/load; 4 loads in flight.
__global__ __launch_bounds__(256) void agg_gather_kernel(
    const unsigned short* __restrict__ xin,
    const int* __restrict__ nbr, const int* __restrict__ rowstart,
    unsigned short* __restrict__ aggb) {
    int wave = threadIdx.x >> 6, lane = threadIdx.x & 63;
    int node = blockIdx.x * 4 + wave;
    if (node >= NN) return;
    int part = lane >> 4;                    // 0..3: which neighbor in group of 4
    int col8 = (lane & 15) * 8;              // 8 feats per lane
    int beg = rowstart[node], end = rowstart[node + 1];
    float a[8] = {0,0,0,0,0,0,0,0};
    float b[8] = {0,0,0,0,0,0,0,0};
    int j = beg + part;
    for (; j + 12 < end; j += 16) {          // 4 outstanding 16B loads, 16 nbrs/wave in flight
        int s0 = nbr[j], s1 = nbr[j + 4], s2 = nbr[j + 8], s3 = nbr[j + 12];
        bf16x8 v0 = *(const bf16x8*)(xin + (size_t)s0 * F + col8);
        bf16x8 v1 = *(const bf16x8*)(xin + (size_t)s1 * F + col8);
        bf16x8 v2 = *(const bf16x8*)(xin + (size_t)s2 * F + col8);
        bf16x8 v3 = *(const bf16x8*)(xin + (size_t)s3 * F + col8);
        for (int i = 0; i < 8; i++) a[i] += b2f((unsigned short)v0[i]);
        for (int i = 0; i < 8; i++) b[i] += b2f((unsigned short)v1[i]);
        for (int i = 0; i < 8; i++) a[i] += b2f((unsigned short)v2[i]);
        for (int i = 0; i < 8; i++) b[i] += b2f((unsigned short)v3[i]);
    }
    for (; j < end; j += 4) {
        int s0 = nbr[j];
        bf16x8 v0 = *(const bf16x8*)(xin + (size_t)s0 * F + col8);
        for (int i = 0; i < 8; i++) a[i] += b2f((unsigned short)v0[i]);
    }
    float inv = 1.0f / fmaxf((float)(end - beg), 1.0f);
    unsigned short o[8];
    for (int i = 0; i < 8; i++) {
        float v = a[i] + b[i];
        v += __shfl_xor(v, 16);
        v += __shfl_xor(v, 32);
        o[i] = f2b(v * inv);
    }
    if (part == 0)
        *(bf16x8*)(aggb + (size_t)node * F + col8) = *(bf16x8*)o;
}

// ---------------- fused SAGE combine: out = relu(A1@W1^T + bias + A2@W2^T) ----------------
__global__ __launch_bounds__(256) void node_gemm_kernel(
    const unsigned short* __restrict__ A1, const unsigned short* __restrict__ A2,
    const unsigned short* __restrict__ W1, const unsigned short* __restrict__ W2,
    const float* __restrict__ bias,
    unsigned short* __restrict__ out) {
    int wave = threadIdx.x >> 6, lane = threadIdx.x & 63;
    int c = lane & 15, q = lane >> 4;
    int m0 = (blockIdx.x * 4 + wave) * 16;
    if (m0 >= NN) return;
    f32x4 acc[8];
    for (int nt = 0; nt < 8; nt++) {
        float b = bias[nt * 16 + c];
        acc[nt] = (f32x4){b, b, b, b};
    }
    int mrow = m0 + c; if (mrow > NN - 1) mrow = NN - 1;
    for (int op = 0; op < 2; op++) {
        const unsigned short* ap = (op ? A2 : A1) + (size_t)mrow * F + q * 8;
        const unsigned short* W  = op ? W2 : W1;
        for (int kb = 0; kb < 4; kb++) {
            bf16x8 a = *(const bf16x8*)(ap + kb * 32);
            for (int nt = 0; nt < 8; nt++) {
                bf16x8 b = *(const bf16x8*)(W + (size_t)(nt * 16 + c) * F + kb * 32 + q * 8);
                acc[nt] = __builtin_amdgcn_mfma_f32_16x16x32_bf16(a, b, acc[nt], 0, 0, 0);
            }
        }
    }
    for (int nt = 0; nt < 8; nt++) {
        for (int r = 0; r < 4; r++) {
            int node = m0 + q * 4 + r;
            if (node < NN) {
                float v = fmaxf(acc[nt][r], 0.0f);
                out[(size_t)node * F + nt * 16 + c] = f2b(v);
            }
        }
    }
}

// ---------------- edge MLP, 32x32x16 MFMA, m-tile OUTER loop ----------------
// 64 edges/wave as two serial 32-edge m-tiles. Per m-tile: af[16] (64 VGPR) gathered once;
// weight quarters staged twice per block (LDS-bound ~1.5x over MFMA) but total reg demand
// ~150 (af 64 + acc0/acc1 32 + po 16 + temps) -> fits 2 waves/SIMD WITHOUT spill
// (R5: spill @cap128; R6: 1 wave/SIMD @290 total regs — both worse).
// Dual nt2 accumulator chains hide MFMA latency.
// A: m=lane&31, k=(lane>>5)*8+j. B: n=lane&31, k=(lane>>5)*8+j.
// C/D: col=lane&31, row=(reg&3)+8*(reg>>2)+4*(lane>>5)  (m74/m101-verified).
__global__ __launch_bounds__(256, 2) void edge_mlp_kernel(
    const unsigned short* __restrict__ h,
    const int* __restrict__ src, const int* __restrict__ dst,
    const unsigned short* __restrict__ wm1f, const float* __restrict__ bm1,
    const float* __restrict__ Wm2, const float* __restrict__ bm2,
    float* __restrict__ out) {
    __shared__ unsigned short wlds[16384];   // 32 KB: one s-quarter
    int t = threadIdx.x;
    int wave = t >> 6, lane = t & 63, c = lane & 31, q5 = lane >> 5;
    int eW = blockIdx.x * 256 + wave * 64;   // wave owns 64 edges = two m-tiles of 32
    float b2 = bm2[0];

    for (int mt = 0; mt < 2; mt++) {
        int e0 = eW + mt * 32;
        int e = e0 + c;
        int sn = src[e], dn = dst[e];

        // gather this m-tile's A-fragments: ef = concat(h[src], h[dst]), k = kf*16 + q5*8
        bf16x8 af[16];
#pragma unroll
        for (int kf = 0; kf < 16; kf++) {
            int k0 = kf * 16 + q5 * 8;
            const unsigned short* base = (k0 < 128) ? (h + (size_t)sn * F) : (h + (size_t)dn * F);
            af[kf] = *(const bf16x8*)(base + (k0 & 127));
        }

        float po[16];
#pragma unroll
        for (int r = 0; r < 16; r++) po[r] = 0.f;

        for (int s = 0; s < 4; s++) {
            __syncthreads();
            const bf16x8* gsrc = (const bf16x8*)(wm1f + s * 16384);
            bf16x8* ldst = (bf16x8*)wlds;
#pragma unroll
            for (int i = 0; i < 8; i++) {
                int idx = i * 256 + t;
                ldst[idx] = gsrc[idx];
            }
            __syncthreads();
            // two independent MFMA chains: nt2=0 and nt2=1
            int o0 = s * 64 + c, o1 = s * 64 + 32 + c;
            float bv0 = bm1[o0], bv1 = bm1[o1];
            f32x16 acc0, acc1;
#pragma unroll
            for (int r = 0; r < 16; r++) { acc0[r] = bv0; acc1[r] = bv1; }
            const bf16x8* b0 = (const bf16x8*)wlds;
            const bf16x8* b1 = (const bf16x8*)wlds + 16 * 64;
#pragma unroll
            for (int ks = 0; ks < 16; ks++) {
                bf16x8 bf0 = b0[ks * 64 + lane];
                bf16x8 bf1 = b1[ks * 64 + lane];
                acc0 = __builtin_amdgcn_mfma_f32_32x32x16_bf16(af[ks], bf0, acc0, 0, 0, 0);
                acc1 = __builtin_amdgcn_mfma_f32_32x32x16_bf16(af[ks], bf1, acc1, 0, 0, 0);
            }
            float w20 = Wm2[o0], w21 = Wm2[o1];
#pragma unroll
            for (int r = 0; r < 16; r++)
                po[r] += fmaxf(acc0[r], 0.0f) * w20 + fmaxf(acc1[r], 0.0f) * w21;
        }
        // reduce over the 32 output cols (lanes differing in bits 0..4)
#pragma unroll
        for (int r = 0; r < 16; r++) {
            float v = po[r];
            v += __shfl_xor(v, 1);
            v += __shfl_xor(v, 2);
            v += __shfl_xor(v, 4);
            v += __shfl_xor(v, 8);
            v += __shfl_xor(v, 16);
            if (c == 0) {
                int row = (r & 3) + 8 * (r >> 2) + 4 * q5;
                out[e0 + row] = v + b2;
            }
        }
    }
}

extern "C" void kernel_launch(void* const* d_in, const int* in_sizes, int n_in,
                              void* d_out, int out_size, void* d_ws, size_t ws_size,
                              hipStream_t stream) {
    const float* x   = (const float*)d_in[0];
    const int*   ei  = (const int*)d_in[1];
    const float* W1l = (const float*)d_in[2];
    const float* b1l = (const float*)d_in[3];
    const float* W1r = (const float*)d_in[4];
    const float* W2l = (const float*)d_in[5];
    const float* b2l = (const float*)d_in[6];
    const float* W2r = (const float*)d_in[7];
    const float* Wm1 = (const float*)d_in[8];
    const float* bm1 = (const float*)d_in[9];
    const float* Wm2 = (const float*)d_in[10];
    const float* bm2 = (const float*)d_in[11];

    char* ws = (char*)d_ws;
    unsigned short* xb       = (unsigned short*)(ws);
    unsigned short* h1       = (unsigned short*)(ws + 12800000);
    unsigned short* h2       = (unsigned short*)(ws + 25600000);
    unsigned short* aggb     = (unsigned short*)(ws + 38400000);
    unsigned short* wb       = (unsigned short*)(ws + 51200000);
    int*            s32      = (int*)(ws + 51462144);
    int*            d32      = (int*)(ws + 54662144);
    int*            deg      = (int*)(ws + 57862144);
    int*            rowstart = (int*)(ws + 58062208);
    int*            cursor   = (int*)(ws + 58262272);
    int*            nbr      = (int*)(ws + 58462336);
    float*          outp     = (float*)d_out;

    const unsigned short* w1l_b = wb;
    const unsigned short* w1r_b = wb + 16384;
    const unsigned short* w2l_b = wb + 32768;
    const unsigned short* w2r_b = wb + 49152;
    unsigned short*       wm1f  = wb + 65536;        // 65536 elems, fragment-ordered

    // prep: casts + fragment reorder + indices + CSR build
    cast_x_kernel<<<6250, 256, 0, stream>>>(x, xb);
    cast_w_kernel<<<64, 256, 0, stream>>>(W1l, W1r, W2l, W2r, wb);
    frag_wm1_kernel<<<32, 256, 0, stream>>>(Wm1, wm1f);
    edge_cvt_kernel<<<3125, 256, 0, stream>>>(ei, s32, d32);
    hipMemsetAsync(deg, 0, 200064, stream);
    hist_kernel<<<3125, 256, 0, stream>>>(d32, deg);
    scan_kernel<<<1, 1024, 0, stream>>>(deg, rowstart, cursor);
    fill_kernel<<<3125, 256, 0, stream>>>(s32, d32, cursor, nbr);

    // layer 1
    agg_gather_kernel<<<12500, 256, 0, stream>>>(xb, nbr, rowstart, aggb);
    node_gemm_kernel<<<782, 256, 0, stream>>>(aggb, xb, w1l_b, w1r_b, b1l, h1);
    // layer 2
    agg_gather_kernel<<<12500, 256, 0, stream>>>(h1, nbr, rowstart, aggb);
    node_gemm_kernel<<<782, 256, 0, stream>>>(aggb, h1, w2l_b, w2r_b, b2l, h2);
    // edge MLP
    edge_mlp_kernel<<<3125, 256, 0, stream>>>(h2, s32, d32, wm1f, bm1, Wm2, bm2, outp);
}